// Round 15
// baseline (132.283 us; speedup 1.0000x reference)
//
#include <hip/hip_runtime.h>
#include <math.h>

typedef unsigned short u16;
typedef __bf16 bf16x8 __attribute__((ext_vector_type(8)));
typedef float floatx4 __attribute__((ext_vector_type(4)));

#define S_LEN 2048
#define NBATCH 4

__device__ __forceinline__ u16 f2bf(float f) {
  union { float f; unsigned u; } v; v.f = f;
  unsigned r = v.u + 0x7FFFu + ((v.u >> 16) & 1u);
  return (u16)(r >> 16);
}

__device__ __forceinline__ void gload_lds16(const void* g, void* l) {
  __builtin_amdgcn_global_load_lds(
      (__attribute__((address_space(1))) const void*)g,
      (__attribute__((address_space(3))) void*)l, 16, 0, 0);
}

// ---------------- core C = A * B^T (proven 2-phase 128x128, BK=64) ----------------
// WAVES=4 / WAVES=8 proven rounds 5..14; npass loop proven round 13.
// EPI: 1 = bf16 store; 2 = scores exp+mask+atomic row sums; 3 = fp32 / sums[row].
template <int EPI, int BM, int WAVES>
__device__ __forceinline__ void gemm_core(
    const u16* __restrict__ A, const u16* __restrict__ B, void* __restrict__ Cv,
    int n0, int lda, int ldb, int ldc, float scale,
    float* __restrict__ sums, int diag, int npass,
    int m0_0, int Keff_0, int m0_1, int Keff_1) {
  constexpr int ABYTES = BM * 128;
  constexpr int ASLOTS = (BM * 128 / 1024) / WAVES;
  constexpr int BSLOTS = 16 / WAVES;
  constexpr int WROWS = BM / (WAVES / 2);
  constexpr int MFR = WROWS / 16;
  constexpr int HALF = ABYTES + 16384;

  __shared__ u16 lds_t[2 * (BM * 64 + 128 * 64)];
  char* ldsc = (char*)lds_t;

  const int t = threadIdx.x, wave = t >> 6, lane = t & 63;
  const int wm = wave >> 1, wn = wave & 1;
  const int ra0 = wm * WROWS + (lane & 15);
  const int rb0 = wn * 64 + (lane & 15);
  const int cb0 = (lane >> 4) * 16;

  for (int p = 0; p < npass; ++p) {
    const int m0 = p ? m0_1 : m0_0;
    const int Keff = p ? Keff_1 : Keff_0;

    const char* pA[ASLOTS]; char* dA[ASLOTS];
    const char* pB[BSLOTS]; char* dB[BSLOTS];
#pragma unroll
    for (int j = 0; j < ASLOTS; ++j) {
      int o = (j * WAVES + wave) * 1024 + lane * 16;
      int g = o ^ (((o >> 7) & 7) << 4);
      int row = g >> 7, colb = g & 127;
      pA[j] = (const char*)A + ((size_t)(m0 + row) * lda) * 2 + colb;
      dA[j] = ldsc + (j * WAVES + wave) * 1024;
    }
#pragma unroll
    for (int j = 0; j < BSLOTS; ++j) {
      int o = (j * WAVES + wave) * 1024 + lane * 16;
      int g = o ^ (((o >> 7) & 7) << 4);
      int row = g >> 7, colb = g & 127;
      pB[j] = (const char*)B + ((size_t)(n0 + row) * ldb) * 2 + colb;
      dB[j] = ldsc + ABYTES + (j * WAVES + wave) * 1024;
    }

    auto STAGE = [&](int buf, int k0) {
      const int bo = buf * HALF;
#pragma unroll
      for (int j = 0; j < ASLOTS; ++j) gload_lds16(pA[j] + (size_t)k0 * 2, dA[j] + bo);
#pragma unroll
      for (int j = 0; j < BSLOTS; ++j) gload_lds16(pB[j] + (size_t)k0 * 2, dB[j] + bo);
    };

    floatx4 acc[MFR][4];
#pragma unroll
    for (int i = 0; i < MFR; ++i)
#pragma unroll
      for (int j = 0; j < 4; ++j) acc[i][j] = (floatx4){0.f, 0.f, 0.f, 0.f};

    STAGE(0, 0);
    int cur = 0;
    for (int k0 = 0; k0 < Keff; k0 += 64) {
      const int kn = k0 + 64;
      if (kn < Keff) {
        STAGE(cur ^ 1, kn);
        if constexpr (ASLOTS + BSLOTS == 4) asm volatile("s_waitcnt vmcnt(4)" ::: "memory");
        else if constexpr (ASLOTS + BSLOTS == 6) asm volatile("s_waitcnt vmcnt(6)" ::: "memory");
        else                                asm volatile("s_waitcnt vmcnt(8)" ::: "memory");
      } else {
        asm volatile("s_waitcnt vmcnt(0)" ::: "memory");
      }
      __builtin_amdgcn_s_barrier();
      __builtin_amdgcn_sched_barrier(0);

      const int bo = cur * HALF;
      bf16x8 af[2][MFR], bfv[2][4];
#pragma unroll
      for (int kk = 0; kk < 2; ++kk) {
#pragma unroll
        for (int f = 0; f < MFR; ++f) {
          int rA = ra0 + f * 16;
          int oA = rA * 128 + kk * 64 + cb0; oA ^= ((rA & 7) << 4);
          af[kk][f] = *(const bf16x8*)(ldsc + bo + oA);
        }
#pragma unroll
        for (int f = 0; f < 4; ++f) {
          int rB = rb0 + f * 16;
          int oB = rB * 128 + kk * 64 + cb0; oB ^= ((rB & 7) << 4);
          bfv[kk][f] = *(const bf16x8*)(ldsc + bo + ABYTES + oB);
        }
      }
      __builtin_amdgcn_s_setprio(1);
#pragma unroll
      for (int kk = 0; kk < 2; ++kk)
#pragma unroll
        for (int mI = 0; mI < MFR; ++mI)
#pragma unroll
          for (int nI = 0; nI < 4; ++nI)
            acc[mI][nI] = __builtin_amdgcn_mfma_f32_16x16x32_bf16(
                af[kk][mI], bfv[kk][nI], acc[mI][nI], 0, 0, 0);
      __builtin_amdgcn_s_setprio(0);

      __builtin_amdgcn_sched_barrier(0);
      __builtin_amdgcn_s_barrier();
      cur ^= 1;
    }

    const int crow0 = m0 + wm * WROWS + ((lane >> 4) * 4);
    const int ccol0 = n0 + wn * 64 + (lane & 15);
    if constexpr (EPI == 1) {
      u16* C = (u16*)Cv;
#pragma unroll
      for (int mI = 0; mI < MFR; ++mI)
#pragma unroll
        for (int r = 0; r < 4; ++r) {
          size_t ro = (size_t)(crow0 + mI * 16 + r) * ldc + ccol0;
#pragma unroll
          for (int nI = 0; nI < 4; ++nI)
            C[ro + nI * 16] = f2bf(acc[mI][nI][r] * scale);
        }
    } else if constexpr (EPI == 2) {
      u16* C = (u16*)Cv;
#pragma unroll
      for (int mI = 0; mI < MFR; ++mI)
#pragma unroll
        for (int r = 0; r < 4; ++r) {
          const int row = crow0 + mI * 16 + r;
          size_t ro = (size_t)row * ldc + ccol0;
          float ls = 0.f;
#pragma unroll
          for (int nI = 0; nI < 4; ++nI) {
            const int col = ccol0 + nI * 16;
            float pp = __expf(acc[mI][nI][r] * scale);
            if (diag && col > row) pp = 0.f;
            C[ro + nI * 16] = f2bf(pp);
            ls += pp;
          }
          ls += __shfl_xor(ls, 1); ls += __shfl_xor(ls, 2);
          ls += __shfl_xor(ls, 4); ls += __shfl_xor(ls, 8);
          if ((lane & 15) == 0) atomicAdd(&sums[row], ls);
        }
    } else {
      float* C = (float*)Cv;
#pragma unroll
      for (int mI = 0; mI < MFR; ++mI)
#pragma unroll
        for (int r = 0; r < 4; ++r) {
          const int row = crow0 + mI * 16 + r;
          float inv = 1.0f;
          if (sums) inv = 1.0f / sums[row];
          size_t ro = (size_t)row * ldc + ccol0;
#pragma unroll
          for (int nI = 0; nI < 4; ++nI)
            C[ro + nI * 16] = acc[mI][nI][r] * inv;
        }
    }
  }
}

// ---------------- D1: Wq/Wk bf16 casts (2048) + sums = 0 (32) ----------------
__global__ __launch_bounds__(256) void prep_w(const float* __restrict__ Wq,
                                              const float* __restrict__ Wk,
                                              u16* __restrict__ Wqb,
                                              u16* __restrict__ Wkb,
                                              float* __restrict__ sums) {
  const int b = blockIdx.x, t = threadIdx.x;
  if (b < 2048) {
    const float4* W4 = (const float4*)((b < 1024) ? Wq : Wk);
    u16* T = (b < 1024) ? Wqb : Wkb;
    int i = (b & 1023) * 256 + t;            // 262144 float4 per W
    float4 v = W4[i];
    ushort4 o;
    o.x = f2bf(v.x); o.y = f2bf(v.y); o.z = f2bf(v.z); o.w = f2bf(v.w);
    ((ushort4*)T)[i] = o;
  } else {
    sums[(b - 2048) * 256 + t] = 0.0f;       // 32 x 256 = 8192 floats
  }
}

// ---- D2: Mt = Wk Wq^T (blocks 0..63, MFMA) || xb convert (64..2111) || Wv^T (2112..3135) ----
// Mt's ~11 us latency hides under 54 MB of streaming in the same dispatch.
__global__ __launch_bounds__(256) void prep_x_mt(const float4* __restrict__ x4,
                                                 u16* __restrict__ xb,
                                                 const float* __restrict__ Wv,
                                                 u16* __restrict__ Wvt,
                                                 const u16* __restrict__ Wqb,
                                                 const u16* __restrict__ Wkb,
                                                 u16* __restrict__ Mt) {
  const int b = blockIdx.x, t = threadIdx.x;
  if (b < 64) {
    // Mt[d2][d1] = sum_e Wkb[d2,e] Wqb[d1,e]
    gemm_core<1, 128, 4>(Wkb, Wqb, Mt, (b & 7) * 128, 1024, 1024, 1024, 1.0f,
                         nullptr, 0, 1, (b >> 3) * 128, 1024, 0, 0);
  } else if (b < 2112) {
    const int i0 = (b - 64) * 1024 + t;      // 2048 blocks x 4 float4/thread
#pragma unroll
    for (int j = 0; j < 4; ++j) {
      int i = i0 + j * 256;
      float4 v = x4[i];
      ushort4 o;
      o.x = f2bf(v.x); o.y = f2bf(v.y); o.z = f2bf(v.z); o.w = f2bf(v.w);
      ((ushort4*)xb)[i] = o;
    }
  } else {
    const int r2 = b - 2112;                 // [0,1024): 32x32 tiles of Wv^T
    __shared__ float tile[32][33];
    const int e0 = (r2 & 31) * 32, d0 = (r2 >> 5) * 32;
    const int tx = t & 31, ty = t >> 5;
#pragma unroll
    for (int j = ty; j < 32; j += 8)
      tile[j][tx] = Wv[(size_t)(d0 + j) * 1024 + e0 + tx];
    __syncthreads();
#pragma unroll
    for (int j = ty; j < 32; j += 8)
      Wvt[(size_t)(e0 + j) * 1024 + d0 + tx] = f2bf(tile[tx][j]);
  }
}

// ---- D3: vt (512 tiles) + y (512 tiles) in one dispatch, xb-panel-aligned per XCD ----
// XCD x handles vt columns [x*1024,(x+1)*1024) and y rows [x*1024,(x+1)*1024):
// both read the SAME 2 MB xb panel -> L2-resident. Single gemm_core call site.
__global__ __launch_bounds__(256) void vt_y_kernel(const u16* __restrict__ xb,
                                                   const u16* __restrict__ Wvt,
                                                   const u16* __restrict__ Mt,
                                                   u16* __restrict__ vt,
                                                   u16* __restrict__ y) {
  const int id = blockIdx.x;
  const int xcd = id & 7, slot = id >> 3;    // slot in [0,128)
  const u16 *A, *B; u16* C; int m0, n0, ldc;
  if (slot < 64) {
    // vt tile: vt[e][s] = sum_d Wvt[e,d] xb[s,d]
    A = Wvt; B = xb; C = vt; ldc = 8192;
    m0 = (slot >> 3) * 128;                  // e panel (0..1023)
    n0 = (xcd * 8 + (slot & 7)) * 128;       // s columns in this XCD's panel
  } else {
    // y tile: y[s,e'] = sum_d xb[s,d] Mt[e',d]
    const int s = slot - 64;
    A = xb; B = Mt; C = y; ldc = 1024;
    m0 = (xcd * 8 + (s >> 3)) * 128;         // s rows in this XCD's panel
    n0 = (s & 7) * 128;
  }
  gemm_core<1, 128, 4>(A, B, C, n0, 1024, 1024, ldc, 1.0f, nullptr, 0,
                       1, m0, 1024, 0, 0);
}

// ---------------- scores: P~ = exp(y xb^T / 32) bf16 + atomic row sums (8-wave) ----------------
__global__ __launch_bounds__(512) void gemm_scores(const u16* __restrict__ y,
                                                   const u16* __restrict__ xb,
                                                   u16* __restrict__ sc16,
                                                   float* __restrict__ sums) {
  const int lin = blockIdx.x;
  const int g = (lin & 7) * 68 + (lin >> 3);         // bijective: 544 = 8*68
  const int z = g / 136, t = g - z * 136;
  int bi = (int)((sqrtf(8.f * (float)t + 1.f) - 1.f) * 0.5f);
  while ((bi + 1) * (bi + 2) / 2 <= t) ++bi;
  while (bi * (bi + 1) / 2 > t) --bi;
  const int bj = t - bi * (bi + 1) / 2;
  gemm_core<2, 128, 8>(y + (size_t)z * 2097152, xb + (size_t)z * 2097152,
                       sc16 + (size_t)z * 4194304,
                       bj * 128, 1024, 1024, 2048, 0.03125f,
                       sums + z * 2048, (bi == bj) ? 1 : 0,
                       1, bi * 128, 1024, 0, 0);
}

// ---------------- PV paired (8-wave): block does tiles bi=15-y THEN bi=y ----------------
__global__ __launch_bounds__(512) void gemm_pv(const u16* __restrict__ sc16,
                                               const u16* __restrict__ vt,
                                               float* __restrict__ out,
                                               float* __restrict__ sums) {
  const int bj = blockIdx.x, z = blockIdx.z, yb = blockIdx.y;  // yb in [0,8)
  const int bi1 = 15 - yb, bi2 = yb;                           // big first
  gemm_core<3, 128, 8>(sc16 + (size_t)z * 4194304, vt + (size_t)z * 2048,
                       out + (size_t)z * 2097152,
                       bj * 128, 2048, 8192, 1024, 1.0f,
                       sums + z * 2048, 0,
                       2, bi1 * 128, (bi1 + 1) * 128, bi2 * 128, (bi2 + 1) * 128);
}

// ---------------- launch ----------------
extern "C" void kernel_launch(void* const* d_in, const int* in_sizes, int n_in,
                              void* d_out, int out_size, void* d_ws, size_t ws_size,
                              hipStream_t stream) {
  const float* x  = (const float*)d_in[0];
  const float* Wq = (const float*)d_in[1];
  const float* Wk = (const float*)d_in[2];
  const float* Wv = (const float*)d_in[3];
  float* out = (float*)d_out;
  char* ws = (char*)d_ws;

  const size_t MB = 1ull << 20;
  u16*  xb   = (u16*)(ws);              // 16 MiB : x bf16           [8192][1024]
  u16*  Wvt  = (u16*)(ws + 16 * MB);    //  2 MiB : Wv^T bf16        [1024][1024]
  u16*  Wqb  = (u16*)(ws + 18 * MB);    //  2 MiB : Wq bf16          [1024][1024]
  u16*  Wkb  = (u16*)(ws + 20 * MB);    //  2 MiB : Wk bf16          [1024][1024]
  u16*  Mt   = (u16*)(ws + 22 * MB);    //  2 MiB : (Wk Wq^T) bf16   [1024][1024]
  u16*  y    = (u16*)(ws + 24 * MB);    // 16 MiB : x (WqWk^T) bf16  [8192][1024]
  u16*  vt   = (u16*)(ws + 40 * MB);    // 16 MiB : v^T bf16         [1024][8192]
  u16*  sc16 = (u16*)(ws + 56 * MB);    // 32 MiB : P~ bf16          [4][2048][2048]
  float* sums = (float*)(ws + 88 * MB); // 32 KiB : row sums         [4][2048]

  // D1: Wq/Wk casts + sums=0
  prep_w<<<2080, 256, 0, stream>>>(Wq, Wk, Wqb, Wkb, sums);

  // D2: Mt (MFMA, blocks 0..63) || xb convert || Wv^T — Mt hides under streaming
  prep_x_mt<<<3136, 256, 0, stream>>>((const float4*)x, xb, Wv, Wvt, Wqb, Wkb, Mt);

  // D3: vt + y, 1024 blocks = 2 clean rounds, xb-panel-aligned per XCD
  vt_y_kernel<<<1024, 256, 0, stream>>>(xb, Wvt, Mt, vt, y);

  // P~ = exp(y xb^T / 32) bf16 + row sums : 544 blocks x 512 threads
  gemm_scores<<<544, 512, 0, stream>>>(y, xb, sc16, sums);

  // out = P~ V / rowsum : 256 blocks x 512 threads, perfectly paired
  gemm_pv<<<dim3(8, 8, 4), 512, 0, stream>>>(sc16, vt, out, sums);
}

// Round 16
// 119.948 us; speedup vs baseline: 1.1028x; 1.1028x over previous
//
#include <hip/hip_runtime.h>
#include <math.h>

typedef unsigned short u16;
typedef __bf16 bf16x8 __attribute__((ext_vector_type(8)));
typedef float floatx4 __attribute__((ext_vector_type(4)));

#define S_LEN 2048
#define NBATCH 4

__device__ __forceinline__ u16 f2bf(float f) {
  union { float f; unsigned u; } v; v.f = f;
  unsigned r = v.u + 0x7FFFu + ((v.u >> 16) & 1u);
  return (u16)(r >> 16);
}

__device__ __forceinline__ void gload_lds16(const void* g, void* l) {
  __builtin_amdgcn_global_load_lds(
      (__attribute__((address_space(1))) const void*)g,
      (__attribute__((address_space(3))) void*)l, 16, 0, 0);
}

// -------- fused prep (R14-proven): xb (0..8191) | Wq,Wk bf16 cast (8192..10239) |
//          Wv transpose cast (10240..11263) | sums = 0 (11264..11295) --------
__global__ __launch_bounds__(256) void prep_kernel(const float4* __restrict__ x4,
                                                   u16* __restrict__ xb,
                                                   const float* __restrict__ Wq,
                                                   const float* __restrict__ Wk,
                                                   const float* __restrict__ Wv,
                                                   u16* __restrict__ Wqb,
                                                   u16* __restrict__ Wkb,
                                                   u16* __restrict__ Wvt,
                                                   float* __restrict__ sums) {
  const int b = blockIdx.x, t = threadIdx.x;
  if (b < 8192) {
    int i = b * 256 + t;                     // n4 = 2,097,152 exactly
    float4 v = x4[i];
    ushort4 o;
    o.x = f2bf(v.x); o.y = f2bf(v.y); o.z = f2bf(v.z); o.w = f2bf(v.w);
    ((ushort4*)xb)[i] = o;
  } else if (b < 10240) {
    const int idx = b - 8192;                // [0, 2048): 1024 for Wq, 1024 for Wk
    const float4* W4 = (const float4*)((idx < 1024) ? Wq : Wk);
    u16* T = (idx < 1024) ? Wqb : Wkb;
    int i = (idx & 1023) * 256 + t;          // 262144 float4 per W
    float4 v = W4[i];
    ushort4 o;
    o.x = f2bf(v.x); o.y = f2bf(v.y); o.z = f2bf(v.z); o.w = f2bf(v.w);
    ((ushort4*)T)[i] = o;
  } else if (b < 11264) {
    const int r2 = b - 10240;                // [0, 1024): 32x32 tiles of Wv^T
    __shared__ float tile[32][33];
    const int e0 = (r2 & 31) * 32, d0 = (r2 >> 5) * 32;
    const int tx = t & 31, ty = t >> 5;      // (32,8)
#pragma unroll
    for (int j = ty; j < 32; j += 8)
      tile[j][tx] = Wv[(size_t)(d0 + j) * 1024 + e0 + tx];
    __syncthreads();
#pragma unroll
    for (int j = ty; j < 32; j += 8)
      Wvt[(size_t)(e0 + j) * 1024 + d0 + tx] = f2bf(tile[tx][j]);
  } else {
    sums[(b - 11264) * 256 + t] = 0.0f;      // 32 blocks x 256 = 8192 floats
  }
}

// ---------------- core C = A * B^T (proven 2-phase 128x128, BK=64) ----------------
// WAVES=4 / WAVES=8 proven rounds 5..15; npass loop proven round 13.
// EPI: 1 = bf16 store; 2 = runtime: sums!=0 -> scores exp+mask+atomic row sums,
//      sums==0 -> plain bf16 store (one instantiation serves mixed dispatches);
//      3 = fp32 / sums[row].
template <int EPI, int BM, int WAVES>
__device__ __forceinline__ void gemm_core(
    const u16* __restrict__ A, const u16* __restrict__ B, void* __restrict__ Cv,
    int n0, int lda, int ldb, int ldc, float scale,
    float* __restrict__ sums, int diag, int npass,
    int m0_0, int Keff_0, int m0_1, int Keff_1) {
  constexpr int ABYTES = BM * 128;
  constexpr int ASLOTS = (BM * 128 / 1024) / WAVES;
  constexpr int BSLOTS = 16 / WAVES;
  constexpr int WROWS = BM / (WAVES / 2);
  constexpr int MFR = WROWS / 16;
  constexpr int HALF = ABYTES + 16384;

  __shared__ u16 lds_t[2 * (BM * 64 + 128 * 64)];
  char* ldsc = (char*)lds_t;

  const int t = threadIdx.x, wave = t >> 6, lane = t & 63;
  const int wm = wave >> 1, wn = wave & 1;
  const int ra0 = wm * WROWS + (lane & 15);
  const int rb0 = wn * 64 + (lane & 15);
  const int cb0 = (lane >> 4) * 16;

  for (int p = 0; p < npass; ++p) {
    const int m0 = p ? m0_1 : m0_0;
    const int Keff = p ? Keff_1 : Keff_0;

    const char* pA[ASLOTS]; char* dA[ASLOTS];
    const char* pB[BSLOTS]; char* dB[BSLOTS];
#pragma unroll
    for (int j = 0; j < ASLOTS; ++j) {
      int o = (j * WAVES + wave) * 1024 + lane * 16;
      int g = o ^ (((o >> 7) & 7) << 4);
      int row = g >> 7, colb = g & 127;
      pA[j] = (const char*)A + ((size_t)(m0 + row) * lda) * 2 + colb;
      dA[j] = ldsc + (j * WAVES + wave) * 1024;
    }
#pragma unroll
    for (int j = 0; j < BSLOTS; ++j) {
      int o = (j * WAVES + wave) * 1024 + lane * 16;
      int g = o ^ (((o >> 7) & 7) << 4);
      int row = g >> 7, colb = g & 127;
      pB[j] = (const char*)B + ((size_t)(n0 + row) * ldb) * 2 + colb;
      dB[j] = ldsc + ABYTES + (j * WAVES + wave) * 1024;
    }

    auto STAGE = [&](int buf, int k0) {
      const int bo = buf * HALF;
#pragma unroll
      for (int j = 0; j < ASLOTS; ++j) gload_lds16(pA[j] + (size_t)k0 * 2, dA[j] + bo);
#pragma unroll
      for (int j = 0; j < BSLOTS; ++j) gload_lds16(pB[j] + (size_t)k0 * 2, dB[j] + bo);
    };

    floatx4 acc[MFR][4];
#pragma unroll
    for (int i = 0; i < MFR; ++i)
#pragma unroll
      for (int j = 0; j < 4; ++j) acc[i][j] = (floatx4){0.f, 0.f, 0.f, 0.f};

    STAGE(0, 0);
    int cur = 0;
    for (int k0 = 0; k0 < Keff; k0 += 64) {
      const int kn = k0 + 64;
      if (kn < Keff) {
        STAGE(cur ^ 1, kn);
        if constexpr (ASLOTS + BSLOTS == 4) asm volatile("s_waitcnt vmcnt(4)" ::: "memory");
        else if constexpr (ASLOTS + BSLOTS == 6) asm volatile("s_waitcnt vmcnt(6)" ::: "memory");
        else                                asm volatile("s_waitcnt vmcnt(8)" ::: "memory");
      } else {
        asm volatile("s_waitcnt vmcnt(0)" ::: "memory");
      }
      __builtin_amdgcn_s_barrier();
      __builtin_amdgcn_sched_barrier(0);

      const int bo = cur * HALF;
      bf16x8 af[2][MFR], bfv[2][4];
#pragma unroll
      for (int kk = 0; kk < 2; ++kk) {
#pragma unroll
        for (int f = 0; f < MFR; ++f) {
          int rA = ra0 + f * 16;
          int oA = rA * 128 + kk * 64 + cb0; oA ^= ((rA & 7) << 4);
          af[kk][f] = *(const bf16x8*)(ldsc + bo + oA);
        }
#pragma unroll
        for (int f = 0; f < 4; ++f) {
          int rB = rb0 + f * 16;
          int oB = rB * 128 + kk * 64 + cb0; oB ^= ((rB & 7) << 4);
          bfv[kk][f] = *(const bf16x8*)(ldsc + bo + ABYTES + oB);
        }
      }
      __builtin_amdgcn_s_setprio(1);
#pragma unroll
      for (int kk = 0; kk < 2; ++kk)
#pragma unroll
        for (int mI = 0; mI < MFR; ++mI)
#pragma unroll
          for (int nI = 0; nI < 4; ++nI)
            acc[mI][nI] = __builtin_amdgcn_mfma_f32_16x16x32_bf16(
                af[kk][mI], bfv[kk][nI], acc[mI][nI], 0, 0, 0);
      __builtin_amdgcn_s_setprio(0);

      __builtin_amdgcn_sched_barrier(0);
      __builtin_amdgcn_s_barrier();
      cur ^= 1;
    }

    const int crow0 = m0 + wm * WROWS + ((lane >> 4) * 4);
    const int ccol0 = n0 + wn * 64 + (lane & 15);
    if constexpr (EPI == 1) {
      u16* C = (u16*)Cv;
#pragma unroll
      for (int mI = 0; mI < MFR; ++mI)
#pragma unroll
        for (int r = 0; r < 4; ++r) {
          size_t ro = (size_t)(crow0 + mI * 16 + r) * ldc + ccol0;
#pragma unroll
          for (int nI = 0; nI < 4; ++nI)
            C[ro + nI * 16] = f2bf(acc[mI][nI][r] * scale);
        }
    } else if constexpr (EPI == 2) {
      u16* C = (u16*)Cv;
      if (sums) {
#pragma unroll
        for (int mI = 0; mI < MFR; ++mI)
#pragma unroll
          for (int r = 0; r < 4; ++r) {
            const int row = crow0 + mI * 16 + r;
            size_t ro = (size_t)row * ldc + ccol0;
            float ls = 0.f;
#pragma unroll
            for (int nI = 0; nI < 4; ++nI) {
              const int col = ccol0 + nI * 16;
              float pp = __expf(acc[mI][nI][r] * scale);
              if (diag && col > row) pp = 0.f;
              C[ro + nI * 16] = f2bf(pp);
              ls += pp;
            }
            ls += __shfl_xor(ls, 1); ls += __shfl_xor(ls, 2);
            ls += __shfl_xor(ls, 4); ls += __shfl_xor(ls, 8);
            if ((lane & 15) == 0) atomicAdd(&sums[row], ls);
          }
      } else {
#pragma unroll
        for (int mI = 0; mI < MFR; ++mI)
#pragma unroll
          for (int r = 0; r < 4; ++r) {
            size_t ro = (size_t)(crow0 + mI * 16 + r) * ldc + ccol0;
#pragma unroll
            for (int nI = 0; nI < 4; ++nI)
              C[ro + nI * 16] = f2bf(acc[mI][nI][r] * scale);
          }
      }
    } else {
      float* C = (float*)Cv;
#pragma unroll
      for (int mI = 0; mI < MFR; ++mI)
#pragma unroll
        for (int r = 0; r < 4; ++r) {
          const int row = crow0 + mI * 16 + r;
          float inv = 1.0f;
          if (sums) inv = 1.0f / sums[row];
          size_t ro = (size_t)(crow0 + mI * 16 + r) * ldc + ccol0;
#pragma unroll
          for (int nI = 0; nI < 4; ++nI)
            C[ro + nI * 16] = acc[mI][nI][r] * inv;
        }
    }
  }
}

// ---- D2: Mt (64 tiles) + vt s-panels 0..55 (448 tiles) = EXACTLY 512 blocks, one round ----
// XCD0 gets all Mt (Wqb/Wkb L2-resident); XCD 1..7 get vt with contiguous s-panels.
__global__ __launch_bounds__(256) void mt_vt(const u16* __restrict__ Wqb,
                                             const u16* __restrict__ Wkb,
                                             const u16* __restrict__ Wvt,
                                             const u16* __restrict__ xb,
                                             u16* __restrict__ Mt,
                                             u16* __restrict__ vt) {
  const int id = blockIdx.x;
  const int lin = (id & 7) * 64 + (id >> 3);         // bijective: 512 = 8*64
  const u16 *A, *B; u16* C; int m0, n0, ldc;
  if (lin < 64) {
    // Mt[d2][d1] = sum_e Wkb[d2,e] Wqb[d1,e]
    A = Wkb; B = Wqb; C = Mt;
    m0 = (lin >> 3) * 128; n0 = (lin & 7) * 128; ldc = 1024;
  } else {
    const int v = lin - 64;                          // [0,448)
    A = Wvt; B = xb; C = vt;
    m0 = (v & 7) * 128; n0 = (v >> 3) * 128; ldc = 8192;  // s-panels 0..55
  }
  gemm_core<1, 128, 4>(A, B, C, n0, 1024, 1024, ldc, 1.0f, nullptr, 0,
                       1, m0, 1024, 0, 0);
}

// -------- D3: y = xb Mt^T : 512 blocks, XCD-chunked (R14-proven) --------
__global__ __launch_bounds__(256) void proj_y(const u16* __restrict__ xb,
                                              const u16* __restrict__ Mt,
                                              u16* __restrict__ y) {
  const int id = blockIdx.x;
  const int lin = (id & 7) * 64 + (id >> 3);         // bijective: 512 = 8*64
  const int bx = lin & 7, by = lin >> 3;
  gemm_core<1, 128, 4>(xb, Mt, y, bx * 128, 1024, 1024, 1024, 1.0f, nullptr, 0,
                       1, by * 128, 1024, 0, 0);
}

// ---- D4: scores (544) + deferred vt s-panels 56..63 (64) = 608 blocks, 8-wave ----
// vt tiles ride in scores' tail round. ONE gemm_core call site (runtime EPI-2 branch).
__global__ __launch_bounds__(512) void scores_vt(const u16* __restrict__ y,
                                                 const u16* __restrict__ xb,
                                                 const u16* __restrict__ Wvt,
                                                 u16* __restrict__ sc16,
                                                 u16* __restrict__ vt,
                                                 float* __restrict__ sums) {
  const int id = blockIdx.x;
  const int g = (id & 7) * 76 + (id >> 3);           // bijective: 608 = 8*76
  const u16 *A, *B; u16* C; int m0, n0, ldc, diag; float scale; float* s;
  if (g < 544) {
    const int z = g / 136, t = g - z * 136;
    int bi = (int)((sqrtf(8.f * (float)t + 1.f) - 1.f) * 0.5f);
    while ((bi + 1) * (bi + 2) / 2 <= t) ++bi;
    while (bi * (bi + 1) / 2 > t) --bi;
    const int bj = t - bi * (bi + 1) / 2;
    A = y + (size_t)z * 2097152; B = xb + (size_t)z * 2097152;
    C = sc16 + (size_t)z * 4194304;
    m0 = bi * 128; n0 = bj * 128; ldc = 2048;
    scale = 0.03125f; s = sums + z * 2048; diag = (bi == bj) ? 1 : 0;
  } else {
    const int v = g - 544;                           // [0,64)
    A = Wvt; B = xb; C = vt;
    m0 = (v & 7) * 128; n0 = (56 + (v >> 3)) * 128; ldc = 8192;
    scale = 1.0f; s = nullptr; diag = 0;
  }
  gemm_core<2, 128, 8>(A, B, C, n0, 1024, 1024, ldc, scale, s, diag,
                       1, m0, 1024, 0, 0);
}

// ---------------- PV paired (8-wave, R13-proven): tiles bi=15-y THEN bi=y ----------------
__global__ __launch_bounds__(512) void gemm_pv(const u16* __restrict__ sc16,
                                               const u16* __restrict__ vt,
                                               float* __restrict__ out,
                                               float* __restrict__ sums) {
  const int bj = blockIdx.x, z = blockIdx.z, yb = blockIdx.y;  // yb in [0,8)
  const int bi1 = 15 - yb, bi2 = yb;                           // big first
  gemm_core<3, 128, 8>(sc16 + (size_t)z * 4194304, vt + (size_t)z * 2048,
                       out + (size_t)z * 2097152,
                       bj * 128, 2048, 8192, 1024, 1.0f,
                       sums + z * 2048, 0,
                       2, bi1 * 128, (bi1 + 1) * 128, bi2 * 128, (bi2 + 1) * 128);
}

// ---------------- launch ----------------
extern "C" void kernel_launch(void* const* d_in, const int* in_sizes, int n_in,
                              void* d_out, int out_size, void* d_ws, size_t ws_size,
                              hipStream_t stream) {
  const float* x  = (const float*)d_in[0];
  const float* Wq = (const float*)d_in[1];
  const float* Wk = (const float*)d_in[2];
  const float* Wv = (const float*)d_in[3];
  float* out = (float*)d_out;
  char* ws = (char*)d_ws;

  const size_t MB = 1ull << 20;
  u16*  xb   = (u16*)(ws);              // 16 MiB : x bf16           [8192][1024]
  u16*  Wvt  = (u16*)(ws + 16 * MB);    //  2 MiB : Wv^T bf16        [1024][1024]
  u16*  Wqb  = (u16*)(ws + 18 * MB);    //  2 MiB : Wq bf16          [1024][1024]
  u16*  Wkb  = (u16*)(ws + 20 * MB);    //  2 MiB : Wk bf16          [1024][1024]
  u16*  Mt   = (u16*)(ws + 22 * MB);    //  2 MiB : (Wk Wq^T) bf16   [1024][1024]
  u16*  y    = (u16*)(ws + 24 * MB);    // 16 MiB : x (WqWk^T) bf16  [8192][1024]
  u16*  vt   = (u16*)(ws + 40 * MB);    // 16 MiB : v^T bf16         [1024][8192]
  u16*  sc16 = (u16*)(ws + 56 * MB);    // 32 MiB : P~ bf16          [4][2048][2048]
  float* sums = (float*)(ws + 88 * MB); // 32 KiB : row sums         [4][2048]

  // D1: xb + W casts + Wv^T + sums=0
  prep_kernel<<<11296, 256, 0, stream>>>((const float4*)x, xb, Wq, Wk, Wv,
                                         Wqb, Wkb, Wvt, sums);

  // D2: Mt + vt(s-panels 0..55) : exactly 512 blocks = one clean round
  mt_vt<<<512, 256, 0, stream>>>(Wqb, Wkb, Wvt, xb, Mt, vt);

  // D3: y = xb Mt^T : 512 blocks
  proj_y<<<512, 256, 0, stream>>>(xb, Mt, y);

  // D4: scores + deferred vt : 608 blocks x 512 threads
  scores_vt<<<608, 512, 0, stream>>>(y, xb, Wvt, sc16, vt, sums);

  // D5: out = P~ V / rowsum : 256 blocks x 512 threads, perfectly paired
  gemm_pv<<<dim3(8, 8, 4), 512, 0, stream>>>(sc16, vt, out, sums);
}